// Round 6
// baseline (64.909 us; speedup 1.0000x reference)
//
#include <hip/hip_runtime.h>
#include <hip/hip_bf16.h>

#define MROWS 65536
#define DD 768
#define HH 64

typedef __attribute__((ext_vector_type(8))) short short8;
typedef __attribute__((ext_vector_type(4))) float f32x4;

// f32 -> bf16 round-to-nearest-even (bit trick; NaN irrelevant for this data)
__device__ inline unsigned short f2bf(float x) {
    union { float f; unsigned u; } v; v.f = x;
    unsigned r = v.u + 0x7fffu + ((v.u >> 16) & 1u);
    return (unsigned short)(r >> 16);
}

// identity buckets <=4, floor(log2)+3 above, clamped [0,9] (exact int version)
__device__ inline int bucket(int c) {
    int idx = (c <= 4) ? c : (34 - __clz(c));   // 31 - clz + 3
    idx = idx < 0 ? 0 : idx;
    return idx > 9 ? 9 : idx;
}

// A/B fragment k-map: lane (g = lane>>4, c0 = lane&15), reg j in [0,8):
//   k = (j>>2)*16 + g*4 + (j&3)      (bijective on [0,32))
// a0 covers bytes [0,64) of the row's 128-B k-chunk, a1 covers [64,128):
// every 64-B granule is read by exactly ONE instruction, once, ever.
// (This is what makes nontemporal A-loads safe now -- round 2's NT regression
// was the old map re-touching granules across two instructions.)
//
// ws layout:
//   Wf    : bf16[24][4][64][8]  = 49152 ushort  (98304 B)  -- W_eff in B-fragment order
//   constv: f32[64]             @ 98304          -- b1 + ment @ W1[768:1536]
//   dlut  : f32[10][64]         @ 98560          -- dist_table @ W1[2304:2324]
//   clut  : f32[10][64]         @ 101120         -- counter_table @ W1[2324:2344]
__global__ __launch_bounds__(1024) void precompute_kernel(
                                  const float* __restrict__ ment,
                                  const float* __restrict__ dist_t,
                                  const float* __restrict__ cnt_t,
                                  const float* __restrict__ W1,
                                  const float* __restrict__ b1,
                                  unsigned short* __restrict__ Wf,
                                  float* __restrict__ constv,
                                  float* __restrict__ dlut,
                                  float* __restrict__ clut) {
    __shared__ float red[1024];
    int b = blockIdx.x;
    if (b < 24) {
        // pack W_eff for k-step s = b: W_eff[d][h] = W1[d][h] + ment[d]*W1[1536+d][h]
        int s = b;
        for (int e = threadIdx.x; e < 2048; e += blockDim.x) {
            int t    = e >> 9;          // n-tile 0..3
            int lane = (e >> 3) & 63;
            int j    = e & 7;
            int d = s * 32 + ((j >> 2) << 4) + (((lane >> 4) & 3) << 2) + (j & 3);
            int h = t * 16 + (lane & 15);
            float v = W1[d * HH + h] + ment[d] * W1[(1536 + d) * HH + h];
            Wf[(size_t)((s * 4 + t) * 64 + lane) * 8 + j] = f2bf(v);
        }
    } else if (b == 24) {
        // constv[h] = b1[h] + sum_d ment[d] * W1[768+d][h]
        // 1024 threads = 64 h x 16 chunks of 48 d each; LDS tree at the end.
        int h = threadIdx.x & 63;
        int chunk = threadIdx.x >> 6;            // 0..15
        float acc = 0.f;
        #pragma unroll 8
        for (int d = chunk * 48; d < chunk * 48 + 48; ++d)
            acc += ment[d] * W1[(768 + d) * HH + h];
        red[threadIdx.x] = acc;
        __syncthreads();
        if (chunk == 0) {
            float s0 = b1[h];
            #pragma unroll
            for (int k = 0; k < 16; ++k) s0 += red[k * 64 + h];
            constv[h] = s0;
        }
    } else if (b == 25) {
        for (int e = threadIdx.x; e < 640; e += blockDim.x) {
            int tt = e >> 6, h = e & 63;
            float a = 0.f;
            #pragma unroll
            for (int k = 0; k < 20; ++k)
                a += dist_t[tt * 20 + k] * W1[(2304 + k) * HH + h];
            dlut[e] = a;
        }
    } else if (b == 26) {
        for (int e = threadIdx.x; e < 640; e += blockDim.x) {
            int tt = e >> 6, h = e & 63;
            float a = 0.f;
            #pragma unroll
            for (int k = 0; k < 20; ++k)
                a += cnt_t[tt * 20 + k] * W1[(2324 + k) * HH + h];
            clut[e] = a;
        }
    }
}

// 32 rows per wave, 512 blocks x 4 waves, no LDS, no barriers.
// Round 6 single change: nontemporal A-loads (zero-reuse 201-MB stream,
// granule-exclusive map) so the stream stops thrashing L2 where the hot
// 96-KB Wf lives. B-loads stay cached.
__global__ __launch_bounds__(256) void score_kernel(
    const float* __restrict__ mem,
    const unsigned short* __restrict__ Wf,
    const float* __restrict__ constv,
    const float* __restrict__ dlut,
    const float* __restrict__ clut,
    const float* __restrict__ W2,
    const float* __restrict__ b2p,
    const int* __restrict__ entc,
    const int* __restrict__ lms,
    const int* __restrict__ msp,
    float* __restrict__ out) {

    int wave = threadIdx.x >> 6;
    int lane = threadIdx.x & 63;
    int g  = lane >> 4;     // 0..3
    int c0 = lane & 15;     // 0..15
    int row0 = blockIdx.x * 128 + wave * 32;    // wave's first row (32 rows)

    if (blockIdx.x == 0 && threadIdx.x == 0) out[MROWS] = 0.0f;  // dummy new-cluster score

    // A sources: row-set 0 = rows row0+c0, row-set 1 = rows row0+16+c0.
    // Within k-step s: a0 at float offset g*4 (first 64-B half), a1 at +16.
    const float* arow0 = mem + (size_t)(row0 + c0) * DD + g * 4;
    const float* arow1 = arow0 + (size_t)16 * DD;

    f32x4 acc[2][4];
    #pragma unroll
    for (int r = 0; r < 2; ++r)
        #pragma unroll
        for (int t = 0; t < 4; ++t)
            acc[r][t] = (f32x4){0.f, 0.f, 0.f, 0.f};

    #pragma unroll 2
    for (int s = 0; s < 24; ++s) {
        f32x4 a0 = __builtin_nontemporal_load((const f32x4*)(arow0 + s * 32));
        f32x4 a1 = __builtin_nontemporal_load((const f32x4*)(arow0 + s * 32 + 16));
        f32x4 d0 = __builtin_nontemporal_load((const f32x4*)(arow1 + s * 32));
        f32x4 d1 = __builtin_nontemporal_load((const f32x4*)(arow1 + s * 32 + 16));

        short8 afA, afB;
        afA[0] = (short)f2bf(a0[0]); afA[1] = (short)f2bf(a0[1]);
        afA[2] = (short)f2bf(a0[2]); afA[3] = (short)f2bf(a0[3]);
        afA[4] = (short)f2bf(a1[0]); afA[5] = (short)f2bf(a1[1]);
        afA[6] = (short)f2bf(a1[2]); afA[7] = (short)f2bf(a1[3]);
        afB[0] = (short)f2bf(d0[0]); afB[1] = (short)f2bf(d0[1]);
        afB[2] = (short)f2bf(d0[2]); afB[3] = (short)f2bf(d0[3]);
        afB[4] = (short)f2bf(d1[0]); afB[5] = (short)f2bf(d1[1]);
        afB[6] = (short)f2bf(d1[2]); afB[7] = (short)f2bf(d1[3]);

        const unsigned short* bp = Wf + (size_t)s * 2048 + lane * 8;
        short8 bf0 = *(const short8*)(bp);
        short8 bf1 = *(const short8*)(bp + 512);
        short8 bf2 = *(const short8*)(bp + 1024);
        short8 bf3 = *(const short8*)(bp + 1536);

        acc[0][0] = __builtin_amdgcn_mfma_f32_16x16x32_bf16(afA, bf0, acc[0][0], 0, 0, 0);
        acc[0][1] = __builtin_amdgcn_mfma_f32_16x16x32_bf16(afA, bf1, acc[0][1], 0, 0, 0);
        acc[0][2] = __builtin_amdgcn_mfma_f32_16x16x32_bf16(afA, bf2, acc[0][2], 0, 0, 0);
        acc[0][3] = __builtin_amdgcn_mfma_f32_16x16x32_bf16(afA, bf3, acc[0][3], 0, 0, 0);
        acc[1][0] = __builtin_amdgcn_mfma_f32_16x16x32_bf16(afB, bf0, acc[1][0], 0, 0, 0);
        acc[1][1] = __builtin_amdgcn_mfma_f32_16x16x32_bf16(afB, bf1, acc[1][1], 0, 0, 0);
        acc[1][2] = __builtin_amdgcn_mfma_f32_16x16x32_bf16(afB, bf2, acc[1][2], 0, 0, 0);
        acc[1][3] = __builtin_amdgcn_mfma_f32_16x16x32_bf16(afB, bf3, acc[1][3], 0, 0, 0);
    }

    // Epilogue. D layout (m89): col = lane&15 (h-tile col), row = g*4 + reg.
    int ms  = msp[0];
    float b2v = b2p[0];
    float cv[4], w2[4];
    #pragma unroll
    for (int t = 0; t < 4; ++t) {
        cv[t] = constv[t * 16 + c0];
        w2[t] = W2[t * 16 + c0];
    }

    #pragma unroll
    for (int r = 0; r < 2; ++r) {
        #pragma unroll
        for (int i = 0; i < 4; ++i) {
            int row = row0 + r * 16 + g * 4 + i;
            int c    = entc[row];
            int dist = ms - lms[row];
            int db = bucket(dist);
            int cb = bucket(c);
            float part = 0.f;
            #pragma unroll
            for (int t = 0; t < 4; ++t) {
                float a = acc[r][t][i];
                int hc = t * 16 + c0;
                float h = a + cv[t] + dlut[db * 64 + hc] + clut[cb * 64 + hc];
                h = fmaxf(h, 0.f);
                part += h * w2[t];
            }
            // reduce across the 16 lanes of this group (lanes share g)
            part += __shfl_xor(part, 8, 64);
            part += __shfl_xor(part, 4, 64);
            part += __shfl_xor(part, 2, 64);
            part += __shfl_xor(part, 1, 64);
            if (c0 == 0)
                out[row] = (c > 0) ? (part + b2v) : -10000.0f;
        }
    }
}

extern "C" void kernel_launch(void* const* d_in, const int* in_sizes, int n_in,
                              void* d_out, int out_size, void* d_ws, size_t ws_size,
                              hipStream_t stream) {
    const float* ment   = (const float*)d_in[0];
    const float* mem    = (const float*)d_in[1];
    const float* dist_t = (const float*)d_in[2];
    const float* cnt_t  = (const float*)d_in[3];
    const float* W1     = (const float*)d_in[4];
    const float* b1     = (const float*)d_in[5];
    const float* W2     = (const float*)d_in[6];
    const float* b2     = (const float*)d_in[7];
    const int*   entc   = (const int*)d_in[8];
    const int*   lmsp   = (const int*)d_in[9];
    const int*   msp    = (const int*)d_in[10];

    unsigned short* Wf = (unsigned short*)d_ws;
    float* constv = (float*)((char*)d_ws + 98304);
    float* dlut   = constv + 64;
    float* clut   = dlut + 640;

    precompute_kernel<<<27, 1024, 0, stream>>>(ment, dist_t, cnt_t, W1, b1, Wf, constv, dlut, clut);
    score_kernel<<<512, 256, 0, stream>>>(mem, Wf, constv, dlut, clut, W2, b2,
                                          entc, lmsp, msp, (float*)d_out);
}

// Round 7
// 45.282 us; speedup vs baseline: 1.4334x; 1.4334x over previous
//
#include <hip/hip_runtime.h>
#include <hip/hip_bf16.h>

#define MROWS 65536
#define DD 768
#define HH 64

typedef __attribute__((ext_vector_type(8))) short short8;
typedef __attribute__((ext_vector_type(4))) float f32x4;

// f32 -> bf16 round-to-nearest-even (bit trick; NaN irrelevant for this data)
__device__ inline unsigned short f2bf(float x) {
    union { float f; unsigned u; } v; v.f = x;
    unsigned r = v.u + 0x7fffu + ((v.u >> 16) & 1u);
    return (unsigned short)(r >> 16);
}

// identity buckets <=4, floor(log2)+3 above, clamped [0,9] (exact int version)
__device__ inline int bucket(int c) {
    int idx = (c <= 4) ? c : (34 - __clz(c));   // 31 - clz + 3
    idx = idx < 0 ? 0 : idx;
    return idx > 9 ? 9 : idx;
}

// A/B fragment k-map: lane (g = lane>>4, c0 = lane&15), reg j in [0,8):
//   k = (j>>2)*16 + g*4 + (j&3)      (bijective on [0,32))
// a0 covers bytes [0,64) of the row's 128-B k-chunk, a1 covers [64,128).
// NOTE: __builtin_nontemporal_load on the A-stream is ~35% SLOWER regardless
// of k-map (measured rounds 2 and 6) -- never reintroduce it.
//
// ws layout:
//   Wf    : bf16[24][4][64][8]  = 49152 ushort  (98304 B)  -- W_eff in B-fragment order
//   constv: f32[64]             @ 98304          -- b1 + ment @ W1[768:1536]
//   dlut  : f32[10][64]         @ 98560          -- dist_table @ W1[2304:2324]
//   clut  : f32[10][64]         @ 101120         -- counter_table @ W1[2324:2344]
__global__ __launch_bounds__(1024) void precompute_kernel(
                                  const float* __restrict__ ment,
                                  const float* __restrict__ dist_t,
                                  const float* __restrict__ cnt_t,
                                  const float* __restrict__ W1,
                                  const float* __restrict__ b1,
                                  unsigned short* __restrict__ Wf,
                                  float* __restrict__ constv,
                                  float* __restrict__ dlut,
                                  float* __restrict__ clut) {
    __shared__ float red[1024];
    int b = blockIdx.x;
    if (b < 24) {
        // pack W_eff for k-step s = b: W_eff[d][h] = W1[d][h] + ment[d]*W1[1536+d][h]
        int s = b;
        for (int e = threadIdx.x; e < 2048; e += blockDim.x) {
            int t    = e >> 9;          // n-tile 0..3
            int lane = (e >> 3) & 63;
            int j    = e & 7;
            int d = s * 32 + ((j >> 2) << 4) + (((lane >> 4) & 3) << 2) + (j & 3);
            int h = t * 16 + (lane & 15);
            float v = W1[d * HH + h] + ment[d] * W1[(1536 + d) * HH + h];
            Wf[(size_t)((s * 4 + t) * 64 + lane) * 8 + j] = f2bf(v);
        }
    } else if (b == 24) {
        // constv[h] = b1[h] + sum_d ment[d] * W1[768+d][h]
        // 1024 threads = 64 h x 16 chunks of 48 d each; LDS tree at the end.
        int h = threadIdx.x & 63;
        int chunk = threadIdx.x >> 6;            // 0..15
        float acc = 0.f;
        #pragma unroll 8
        for (int d = chunk * 48; d < chunk * 48 + 48; ++d)
            acc += ment[d] * W1[(768 + d) * HH + h];
        red[threadIdx.x] = acc;
        __syncthreads();
        if (chunk == 0) {
            float s0 = b1[h];
            #pragma unroll
            for (int k = 0; k < 16; ++k) s0 += red[k * 64 + h];
            constv[h] = s0;
        }
    } else if (b == 25) {
        for (int e = threadIdx.x; e < 640; e += blockDim.x) {
            int tt = e >> 6, h = e & 63;
            float a = 0.f;
            #pragma unroll
            for (int k = 0; k < 20; ++k)
                a += dist_t[tt * 20 + k] * W1[(2304 + k) * HH + h];
            dlut[e] = a;
        }
    } else if (b == 26) {
        for (int e = threadIdx.x; e < 640; e += blockDim.x) {
            int tt = e >> 6, h = e & 63;
            float a = 0.f;
            #pragma unroll
            for (int k = 0; k < 20; ++k)
                a += cnt_t[tt * 20 + k] * W1[(2324 + k) * HH + h];
            clut[e] = a;
        }
    }
}

// 32 rows per wave, 512 blocks x 4 waves, no LDS, no barriers.
// Round 7 single change: super-steps of 4 k-steps -- all 16 A-loads of a
// super-step issued into a register staging array BEFORE any convert/MFMA,
// so bytes [s*128, s*128+512) of each row are in flight together (512-B
// merged DRAM bursts per row-visit instead of 128-B).
__global__ __launch_bounds__(256) void score_kernel(
    const float* __restrict__ mem,
    const unsigned short* __restrict__ Wf,
    const float* __restrict__ constv,
    const float* __restrict__ dlut,
    const float* __restrict__ clut,
    const float* __restrict__ W2,
    const float* __restrict__ b2p,
    const int* __restrict__ entc,
    const int* __restrict__ lms,
    const int* __restrict__ msp,
    float* __restrict__ out) {

    int wave = threadIdx.x >> 6;
    int lane = threadIdx.x & 63;
    int g  = lane >> 4;     // 0..3
    int c0 = lane & 15;     // 0..15
    int row0 = blockIdx.x * 128 + wave * 32;    // wave's first row (32 rows)

    if (blockIdx.x == 0 && threadIdx.x == 0) out[MROWS] = 0.0f;  // dummy new-cluster score

    // A sources: row-set 0 = rows row0+c0, row-set 1 = rows row0+16+c0.
    // Within k-step s: a0 at float offset g*4 (first 64-B half), a1 at +16.
    const float* arow0 = mem + (size_t)(row0 + c0) * DD + g * 4;
    const float* arow1 = arow0 + (size_t)16 * DD;

    f32x4 acc[2][4];
    #pragma unroll
    for (int r = 0; r < 2; ++r)
        #pragma unroll
        for (int t = 0; t < 4; ++t)
            acc[r][t] = (f32x4){0.f, 0.f, 0.f, 0.f};

    for (int ss = 0; ss < 6; ++ss) {            // 6 super-steps x 4 k-steps
        // ---- phase 1: issue all 16 independent A-loads (512 B/row in flight)
        f32x4 st[16];
        #pragma unroll
        for (int q = 0; q < 4; ++q) {
            const float* p0 = arow0 + (ss * 4 + q) * 32;
            const float* p1 = arow1 + (ss * 4 + q) * 32;
            st[q * 4 + 0] = *(const f32x4*)(p0);
            st[q * 4 + 1] = *(const f32x4*)(p0 + 16);
            st[q * 4 + 2] = *(const f32x4*)(p1);
            st[q * 4 + 3] = *(const f32x4*)(p1 + 16);
        }
        // ---- phase 2: convert + B-load + MFMA per k-step
        #pragma unroll
        for (int q = 0; q < 4; ++q) {
            f32x4 a0 = st[q * 4 + 0], a1 = st[q * 4 + 1];
            f32x4 d0 = st[q * 4 + 2], d1 = st[q * 4 + 3];
            short8 afA, afB;
            afA[0] = (short)f2bf(a0[0]); afA[1] = (short)f2bf(a0[1]);
            afA[2] = (short)f2bf(a0[2]); afA[3] = (short)f2bf(a0[3]);
            afA[4] = (short)f2bf(a1[0]); afA[5] = (short)f2bf(a1[1]);
            afA[6] = (short)f2bf(a1[2]); afA[7] = (short)f2bf(a1[3]);
            afB[0] = (short)f2bf(d0[0]); afB[1] = (short)f2bf(d0[1]);
            afB[2] = (short)f2bf(d0[2]); afB[3] = (short)f2bf(d0[3]);
            afB[4] = (short)f2bf(d1[0]); afB[5] = (short)f2bf(d1[1]);
            afB[6] = (short)f2bf(d1[2]); afB[7] = (short)f2bf(d1[3]);

            const unsigned short* bp = Wf + (size_t)(ss * 4 + q) * 2048 + lane * 8;
            short8 bf0 = *(const short8*)(bp);
            short8 bf1 = *(const short8*)(bp + 512);
            short8 bf2 = *(const short8*)(bp + 1024);
            short8 bf3 = *(const short8*)(bp + 1536);

            acc[0][0] = __builtin_amdgcn_mfma_f32_16x16x32_bf16(afA, bf0, acc[0][0], 0, 0, 0);
            acc[0][1] = __builtin_amdgcn_mfma_f32_16x16x32_bf16(afA, bf1, acc[0][1], 0, 0, 0);
            acc[0][2] = __builtin_amdgcn_mfma_f32_16x16x32_bf16(afA, bf2, acc[0][2], 0, 0, 0);
            acc[0][3] = __builtin_amdgcn_mfma_f32_16x16x32_bf16(afA, bf3, acc[0][3], 0, 0, 0);
            acc[1][0] = __builtin_amdgcn_mfma_f32_16x16x32_bf16(afB, bf0, acc[1][0], 0, 0, 0);
            acc[1][1] = __builtin_amdgcn_mfma_f32_16x16x32_bf16(afB, bf1, acc[1][1], 0, 0, 0);
            acc[1][2] = __builtin_amdgcn_mfma_f32_16x16x32_bf16(afB, bf2, acc[1][2], 0, 0, 0);
            acc[1][3] = __builtin_amdgcn_mfma_f32_16x16x32_bf16(afB, bf3, acc[1][3], 0, 0, 0);
        }
    }

    // Epilogue. D layout (m89): col = lane&15 (h-tile col), row = g*4 + reg.
    int ms  = msp[0];
    float b2v = b2p[0];
    float cv[4], w2[4];
    #pragma unroll
    for (int t = 0; t < 4; ++t) {
        cv[t] = constv[t * 16 + c0];
        w2[t] = W2[t * 16 + c0];
    }

    #pragma unroll
    for (int r = 0; r < 2; ++r) {
        #pragma unroll
        for (int i = 0; i < 4; ++i) {
            int row = row0 + r * 16 + g * 4 + i;
            int c    = entc[row];
            int dist = ms - lms[row];
            int db = bucket(dist);
            int cb = bucket(c);
            float part = 0.f;
            #pragma unroll
            for (int t = 0; t < 4; ++t) {
                float a = acc[r][t][i];
                int hc = t * 16 + c0;
                float h = a + cv[t] + dlut[db * 64 + hc] + clut[cb * 64 + hc];
                h = fmaxf(h, 0.f);
                part += h * w2[t];
            }
            // reduce across the 16 lanes of this group (lanes share g)
            part += __shfl_xor(part, 8, 64);
            part += __shfl_xor(part, 4, 64);
            part += __shfl_xor(part, 2, 64);
            part += __shfl_xor(part, 1, 64);
            if (c0 == 0)
                out[row] = (c > 0) ? (part + b2v) : -10000.0f;
        }
    }
}

extern "C" void kernel_launch(void* const* d_in, const int* in_sizes, int n_in,
                              void* d_out, int out_size, void* d_ws, size_t ws_size,
                              hipStream_t stream) {
    const float* ment   = (const float*)d_in[0];
    const float* mem    = (const float*)d_in[1];
    const float* dist_t = (const float*)d_in[2];
    const float* cnt_t  = (const float*)d_in[3];
    const float* W1     = (const float*)d_in[4];
    const float* b1     = (const float*)d_in[5];
    const float* W2     = (const float*)d_in[6];
    const float* b2     = (const float*)d_in[7];
    const int*   entc   = (const int*)d_in[8];
    const int*   lmsp   = (const int*)d_in[9];
    const int*   msp    = (const int*)d_in[10];

    unsigned short* Wf = (unsigned short*)d_ws;
    float* constv = (float*)((char*)d_ws + 98304);
    float* dlut   = constv + 64;
    float* clut   = dlut + 640;

    precompute_kernel<<<27, 1024, 0, stream>>>(ment, dist_t, cnt_t, W1, b1, Wf, constv, dlut, clut);
    score_kernel<<<512, 256, 0, stream>>>(mem, Wf, constv, dlut, clut, W2, b2,
                                          entc, lmsp, msp, (float*)d_out);
}